// Round 2
// baseline (335.137 us; speedup 1.0000x reference)
//
#include <hip/hip_runtime.h>
#include <math.h>

#define BB   1024
#define DD   768
#define HIDV 384
#define MLPH 300
#define MLPP 320   // padded to multiple of 64

typedef float v2f __attribute__((ext_vector_type(2)));

__device__ __forceinline__ float softplusf(float x) {
    return (x > 20.f) ? x : log1pf(expf(x));
}

// ---------------- init: zero accumulators (accum[16] + sumexp[1024]) ----------------
__global__ void k_init(float* __restrict__ ws) {
    int i = blockIdx.x * 256 + threadIdx.x;
    if (i < 16 + BB) ws[i] = 0.f;
}

// ---------------- A: z-reduce + sample + KL, 384 thr/block ----------------
// k_rs is latency-bound: BW scales with resident waves (r1 evidence: 8 vs 10
// waves/CU gave identical 72 us). Max waves: 4 thread-groups of 96, each
// owning one float4 d-chunk of one z-half:
//   g0: z1 mu (d<384, 20 loads)   g1: z1 sigma (d>=384, 20 loads)
//   g2: z2 mu (36 loads)          g3: z2 sigma (36 loads)
// 6 waves/block x 4 blocks/CU = 24 waves/CU (75% cap, 2x round-1).
// Loads batched 9-10 deep to force MLP; VGPR must stay <= 80 for 6 w/SIMD.
__global__ __launch_bounds__(384, 6) void k_rs(
    const float* __restrict__ zl, const float* __restrict__ zv,
    const float* __restrict__ wl, const float* __restrict__ blp,
    const float* __restrict__ wv, const float* __restrict__ bvp,
    const float* __restrict__ eps1, const float* __restrict__ eps2,
    float* __restrict__ s1, float* __restrict__ s2, float* __restrict__ accum)
{
    __shared__ float SG[768];    // sig1 [0,384), sig2 [384,768)
    __shared__ float MU2[384];
    __shared__ float pr[6];
    int tid = threadIdx.x;       // 0..383
    int b = blockIdx.x;
    int g = tid / 96;            // 0..3 (wave-uniform control flow: g<2 <=> tid<192)
    int c = tid - g * 96;        // 0..95: float4 chunk within the 384-wide half

    const float4* p;
    if (g < 2) p = (const float4*)(zl + (size_t)b * 15360) + ((g & 1) * 96 + c);
    else       p = (const float4*)(zv + (size_t)b * 27648) + ((g & 1) * 96 + c);

    float acc[4] = {0.f, 0.f, 0.f, 0.f};
    if (g < 2) {
        #pragma unroll
        for (int t0 = 0; t0 < 20; t0 += 10) {
            float4 vb[10];
            #pragma unroll
            for (int u = 0; u < 10; ++u) vb[u] = p[(t0 + u) * 192];
            #pragma unroll
            for (int u = 0; u < 10; ++u) {
                float w = wl[t0 + u];
                acc[0] = fmaf(vb[u].x, w, acc[0]);
                acc[1] = fmaf(vb[u].y, w, acc[1]);
                acc[2] = fmaf(vb[u].z, w, acc[2]);
                acc[3] = fmaf(vb[u].w, w, acc[3]);
            }
        }
    } else {
        #pragma unroll
        for (int t0 = 0; t0 < 36; t0 += 9) {
            float4 vb[9];
            #pragma unroll
            for (int u = 0; u < 9; ++u) vb[u] = p[(t0 + u) * 192];
            #pragma unroll
            for (int u = 0; u < 9; ++u) {
                float w = wv[t0 + u];
                acc[0] = fmaf(vb[u].x, w, acc[0]);
                acc[1] = fmaf(vb[u].y, w, acc[1]);
                acc[2] = fmaf(vb[u].z, w, acc[2]);
                acc[3] = fmaf(vb[u].w, w, acc[3]);
            }
        }
    }

    float bl = blp[0], bv = bvp[0];

    if (g == 1) {                 // sig1
        float4 o;
        o.x = softplusf(acc[0] + bl) + 1e-7f;
        o.y = softplusf(acc[1] + bl) + 1e-7f;
        o.z = softplusf(acc[2] + bl) + 1e-7f;
        o.w = softplusf(acc[3] + bl) + 1e-7f;
        *(float4*)(SG + c * 4) = o;
    } else if (g == 2) {          // mu2
        *(float4*)(MU2 + c * 4) =
            make_float4(acc[0] + bv, acc[1] + bv, acc[2] + bv, acc[3] + bv);
    } else if (g == 3) {          // sig2
        float4 o;
        o.x = softplusf(acc[0] + bv) + 1e-7f;
        o.y = softplusf(acc[1] + bv) + 1e-7f;
        o.z = softplusf(acc[2] + bv) + 1e-7f;
        o.w = softplusf(acc[3] + bv) + 1e-7f;
        *(float4*)(SG + 384 + c * 4) = o;
    }
    __syncthreads();

    float con = 0.f;
    if (g == 0) {                 // mu1 threads do the sampling + KL for chunk c
        float4 e1v = ((const float4*)eps1)[b * 96 + c];
        float4 e2v = ((const float4*)eps2)[b * 96 + c];
        float4 g1 = *(const float4*)(SG + c * 4);
        float4 m2 = *(const float4*)(MU2 + c * 4);
        float4 g2 = *(const float4*)(SG + 384 + c * 4);
        float e1a[4] = {e1v.x, e1v.y, e1v.z, e1v.w};
        float e2a[4] = {e2v.x, e2v.y, e2v.z, e2v.w};
        float g1a[4] = {g1.x, g1.y, g1.z, g1.w};
        float g2a[4] = {g2.x, g2.y, g2.z, g2.w};
        float m2a[4] = {m2.x, m2.y, m2.z, m2.w};
        float s1o[4], s2o[4];
        #pragma unroll
        for (int j = 0; j < 4; ++j) {
            float mu1 = acc[j] + bl;
            float mu2 = m2a[j];
            float sg1 = g1a[j], sg2 = g2a[j];
            float e1 = e1a[j], e2 = e2a[j];
            float sv1 = fmaf(sg1, e1, mu1);
            float sv2 = fmaf(sg2, e2, mu2);
            s1o[j] = sv1; s2o[j] = sv2;
            float z12 = (sv1 - mu2) / sg2;
            float z21 = (sv2 - mu1) / sg1;
            con += -0.5f * (e1 * e1 + e2 * e2) + 0.5f * z12 * z12 + 0.5f * z21 * z21;
        }
        ((float4*)s1)[b * 96 + c] = make_float4(s1o[0], s1o[1], s1o[2], s1o[3]);
        ((float4*)s2)[b * 96 + c] = make_float4(s2o[0], s2o[1], s2o[2], s2o[3]);
    }

    #pragma unroll
    for (int m = 1; m < 64; m <<= 1) con += __shfl_xor(con, m);
    if ((tid & 63) == 0) pr[tid >> 6] = con;
    __syncthreads();
    if (tid == 0)
        atomicAdd(&accum[0], pr[0] + pr[1] + pr[2] + pr[3] + pr[4] + pr[5]);
}

// ---------------- B: Axb = s1 @ W1x^T + b1 (padded), By = s2 @ W1y^T ----------------
// 32b x 32k tiles, grid (32,10,2) = 640 blocks (~2.5/CU vs 1.25 before).
// LDS padded to 38 (even -> 8B-aligned v2f reads; 152 mod 32 = 24 -> 2-way
// store aliasing, free per G4).
__global__ __launch_bounds__(256) void k_gemm(
    const float* __restrict__ s1, const float* __restrict__ s2,
    const float* __restrict__ W1, const float* __restrict__ b1,
    float* __restrict__ Axb, float* __restrict__ By)
{
    __shared__ __align__(16) float Ss[32][38];   // [h][b]
    __shared__ __align__(16) float Ws[32][38];   // [h][k]
    int z = blockIdx.z;
    const float* S = z ? s2 : s1;
    float* Out = z ? By : Axb;
    int wofs = z ? HIDV : 0;
    int b0 = blockIdx.x * 32;
    int k0 = blockIdx.y * 32;
    int tid = threadIdx.x;
    int row = tid >> 3, q = tid & 7;   // 32 rows x 8 float4 of h
    int krow = k0 + row;
    int tx = tid & 15, ty = tid >> 4;

    float4 ps, pw;
    auto ld = [&](int hc) {
        ps = *(const float4*)&S[(b0 + row) * HIDV + hc + q * 4];
        pw = (krow < MLPH) ? *(const float4*)&W1[krow * DD + wofs + hc + q * 4]
                           : make_float4(0.f, 0.f, 0.f, 0.f);
    };
    ld(0);
    v2f acc[2];
    acc[0] = (v2f){0.f, 0.f}; acc[1] = (v2f){0.f, 0.f};

    for (int ch = 0; ch < 12; ++ch) {
        __syncthreads();
        Ss[q * 4 + 0][row] = ps.x; Ss[q * 4 + 1][row] = ps.y;
        Ss[q * 4 + 2][row] = ps.z; Ss[q * 4 + 3][row] = ps.w;
        Ws[q * 4 + 0][row] = pw.x; Ws[q * 4 + 1][row] = pw.y;
        Ws[q * 4 + 2][row] = pw.z; Ws[q * 4 + 3][row] = pw.w;
        __syncthreads();
        if (ch < 11) ld((ch + 1) * 32);
        #pragma unroll
        for (int h = 0; h < 32; ++h) {
            v2f sv = *(const v2f*)&Ss[h][ty * 2];
            v2f wq = *(const v2f*)&Ws[h][tx * 2];
            acc[0] = __builtin_elementwise_fma((v2f){sv.x, sv.x}, wq, acc[0]);
            acc[1] = __builtin_elementwise_fma((v2f){sv.y, sv.y}, wq, acc[1]);
        }
    }
    #pragma unroll
    for (int i = 0; i < 2; ++i) {
        int bb = b0 + ty * 2 + i;
        int k = k0 + tx * 2;
        float r0 = 0.f, r1 = 0.f;
        if (k < MLPH)     r0 = acc[i].x + (z ? 0.f : b1[k]);
        if (k + 1 < MLPH) r1 = acc[i].y + (z ? 0.f : b1[k + 1]);
        *(v2f*)&Out[bb * MLPP + k] = (v2f){r0, r1};
    }
}

// ---------------- C: T0 sum — one wave per row, float4 loads ----------------
__global__ __launch_bounds__(256) void k_t0(
    const float* __restrict__ Axb, const float* __restrict__ By,
    const float* __restrict__ W2, const float* __restrict__ b2,
    float* __restrict__ accum)
{
    int tid = threadIdx.x;
    int w = tid >> 6, l = tid & 63;
    int b = blockIdx.x * 4 + w;
    const float4* A4 = (const float4*)(Axb + b * MLPP);
    const float4* B4 = (const float4*)(By + b * MLPP);
    const float4* W4 = (const float4*)W2;
    float t = 0.f;
    {
        float4 a = A4[l], bb = B4[l], ww = W4[l];   // k = 4l, 0..255 < 300
        t = fmaf(fmaxf(a.x + bb.x, 0.f), ww.x, t);
        t = fmaf(fmaxf(a.y + bb.y, 0.f), ww.y, t);
        t = fmaf(fmaxf(a.z + bb.z, 0.f), ww.z, t);
        t = fmaf(fmaxf(a.w + bb.w, 0.f), ww.w, t);
    }
    if (l < 11) {                                   // k = 256+4l, up to 296..299
        float4 a = A4[64 + l], bb = B4[64 + l], ww = W4[64 + l];
        t = fmaf(fmaxf(a.x + bb.x, 0.f), ww.x, t);
        t = fmaf(fmaxf(a.y + bb.y, 0.f), ww.y, t);
        t = fmaf(fmaxf(a.z + bb.z, 0.f), ww.z, t);
        t = fmaf(fmaxf(a.w + bb.w, 0.f), ww.w, t);
    }
    #pragma unroll
    for (int m = 1; m < 64; m <<= 1) t += __shfl_xor(t, m);
    if (l == 0) atomicAdd(&accum[1], softplusf(t + b2[0]));
}

// ---------------- D: pair kernel, 32x32 tiles, 1024 blocks (4/CU) ----------------
__global__ __launch_bounds__(256) void k_pairs(
    const float* __restrict__ Axb, const float* __restrict__ By,
    const int* __restrict__ perm, const float* __restrict__ W2,
    const float* __restrict__ b2, float* __restrict__ sumexp)
{
    __shared__ __align__(16) float As[64][38];   // [k][j]
    __shared__ __align__(16) float Bs[64][38];   // [k][i]
    __shared__ float w2s[MLPP];
    int tid = threadIdx.x;
    int j0 = blockIdx.x * 32;
    int i0 = blockIdx.y * 32;
    for (int t = tid; t < MLPP; t += 256) w2s[t] = (t < MLPH) ? W2[t] : 0.f;
    int jj = tid >> 3;         // 0..31 (row: j for As, i for Bs)
    int kk = tid & 7;          // 0..7  (k-float4, x2)
    int tx = tid & 15, ty = tid >> 4;
    int prow = perm[i0 + jj];

    float4 pa[2], pb[2];
    auto ld = [&](int kc) {
        #pragma unroll
        for (int u = 0; u < 2; ++u) {
            int kq = (kk + u * 8) * 4;
            pa[u] = *(const float4*)&Axb[(j0 + jj) * MLPP + kc + kq];
            pb[u] = *(const float4*)&By[prow * MLPP + kc + kq];
        }
    };
    ld(0);
    v2f acc2[2];               // [i2], j-pair packed
    acc2[0] = (v2f){0.f, 0.f};
    acc2[1] = (v2f){0.f, 0.f};

    for (int ch = 0; ch < 5; ++ch) {
        __syncthreads();
        #pragma unroll
        for (int u = 0; u < 2; ++u) {
            int kq = (kk + u * 8) * 4;
            As[kq + 0][jj] = pa[u].x; As[kq + 1][jj] = pa[u].y;
            As[kq + 2][jj] = pa[u].z; As[kq + 3][jj] = pa[u].w;
            Bs[kq + 0][jj] = pb[u].x; Bs[kq + 1][jj] = pb[u].y;
            Bs[kq + 2][jj] = pb[u].z; Bs[kq + 3][jj] = pb[u].w;
        }
        __syncthreads();
        if (ch < 4) ld((ch + 1) * 64);
        int kc = ch * 64;
        #pragma unroll
        for (int k = 0; k < 64; ++k) {
            float w = w2s[kc + k];
            v2f wv2 = (v2f){w, w};
            v2f av = *(const v2f*)&As[k][tx * 2];
            float b0v = Bs[k][ty * 2];
            float b1v = Bs[k][ty * 2 + 1];
            v2f t0v = av + (v2f){b0v, b0v};
            t0v = __builtin_elementwise_max(t0v, (v2f){0.f, 0.f});
            acc2[0] = __builtin_elementwise_fma(t0v, wv2, acc2[0]);
            v2f t1v = av + (v2f){b1v, b1v};
            t1v = __builtin_elementwise_max(t1v, (v2f){0.f, 0.f});
            acc2[1] = __builtin_elementwise_fma(t1v, wv2, acc2[1]);
        }
    }
    float b2v = b2[0];
    #pragma unroll
    for (int i2 = 0; i2 < 2; ++i2) {
        float ssum = (1.f + expf(acc2[i2].x + b2v)) + (1.f + expf(acc2[i2].y + b2v));
        ssum += __shfl_xor(ssum, 1);
        ssum += __shfl_xor(ssum, 2);
        ssum += __shfl_xor(ssum, 4);
        ssum += __shfl_xor(ssum, 8);
        if (tx == 0) atomicAdd(&sumexp[i0 + ty * 2 + i2], ssum);
    }
}

// ---------------- E: final scalar ----------------
__global__ __launch_bounds__(256) void k_final(
    const float* __restrict__ accum, const float* __restrict__ sumexp,
    float* __restrict__ out)
{
    int tid = threadIdx.x;
    float s = 0.f;
    for (int i = tid; i < BB; i += 256) s += logf(sumexp[i]);
    #pragma unroll
    for (int m = 1; m < 64; m <<= 1) s += __shfl_xor(s, m);
    __shared__ float red[4];
    if ((tid & 63) == 0) red[tid >> 6] = s;
    __syncthreads();
    if (tid == 0) {
        float lse_mean = (red[0] + red[1] + red[2] + red[3]) / (float)BB;
        float d_skl = accum[0] / (2.f * (float)BB);
        float t0_mean = accum[1] / (float)BB;
        float lower = t0_mean - (lse_mean - logf((float)BB));
        out[0] = d_skl - lower;
    }
}

extern "C" void kernel_launch(void* const* d_in, const int* in_sizes, int n_in,
                              void* d_out, int out_size, void* d_ws, size_t ws_size,
                              hipStream_t stream)
{
    const float* zl     = (const float*)d_in[0];
    const float* zv     = (const float*)d_in[1];
    const float* fc_l_w = (const float*)d_in[2];
    const float* fc_l_b = (const float*)d_in[3];
    const float* fc_v_w = (const float*)d_in[4];
    const float* fc_v_b = (const float*)d_in[5];
    const float* W1     = (const float*)d_in[6];
    const float* b1     = (const float*)d_in[7];
    const float* W2     = (const float*)d_in[8];
    const float* b2     = (const float*)d_in[9];
    const float* eps1   = (const float*)d_in[10];
    const float* eps2   = (const float*)d_in[11];
    const int*   perm   = (const int*)d_in[12];
    float* out = (float*)d_out;

    float* ws     = (float*)d_ws;
    float* accum  = ws;                    // 16
    float* sumexp = ws + 16;               // 1024
    float* s1     = ws + 16 + BB;          // B*384
    float* s2     = s1 + BB * HIDV;        // B*384
    float* Axb    = s2 + BB * HIDV;        // B*320
    float* By     = Axb + BB * MLPP;       // B*320

    k_init<<<5, 256, 0, stream>>>(ws);
    k_rs<<<BB, 384, 0, stream>>>(zl, zv, fc_l_w, fc_l_b, fc_v_w, fc_v_b,
                                 eps1, eps2, s1, s2, accum);
    k_gemm<<<dim3(32, 10, 2), 256, 0, stream>>>(s1, s2, W1, b1, Axb, By);
    k_t0<<<256, 256, 0, stream>>>(Axb, By, W2, b2, accum);
    k_pairs<<<dim3(32, 32), 256, 0, stream>>>(Axb, By, perm, W2, b2, sumexp);
    k_final<<<1, 256, 0, stream>>>(accum, sumexp, out);
}

// Round 3
// 309.119 us; speedup vs baseline: 1.0842x; 1.0842x over previous
//
#include <hip/hip_runtime.h>
#include <math.h>

#define BB   1024
#define DD   768
#define HIDV 384
#define MLPH 300
#define MLPP 320   // padded to multiple of 64

typedef float v2f __attribute__((ext_vector_type(2)));

__device__ __forceinline__ float softplusf(float x) {
    return (x > 20.f) ? x : log1pf(expf(x));
}

// ---------------- init: zero accumulators (accum[16] + sumexp[1024]) ----------------
__global__ void k_init(float* __restrict__ ws) {
    int i = blockIdx.x * 256 + threadIdx.x;
    if (i < 16 + BB) ws[i] = 0.f;
}

// ---------------- A: z-reduce + sample + KL (UNCHANGED control from r2) ----------------
// r1/r2 evidence: 8/10/16 waves/CU all give ~70us -> per-CU streaming cap
// (~4 B/cyc/CU, MSHR-like), not occupancy. Left as-is this round.
__global__ __launch_bounds__(384, 6) void k_rs(
    const float* __restrict__ zl, const float* __restrict__ zv,
    const float* __restrict__ wl, const float* __restrict__ blp,
    const float* __restrict__ wv, const float* __restrict__ bvp,
    const float* __restrict__ eps1, const float* __restrict__ eps2,
    float* __restrict__ s1, float* __restrict__ s2, float* __restrict__ accum)
{
    __shared__ float SG[768];    // sig1 [0,384), sig2 [384,768)
    __shared__ float MU2[384];
    __shared__ float pr[6];
    int tid = threadIdx.x;       // 0..383
    int b = blockIdx.x;
    int g = tid / 96;            // 0..3
    int c = tid - g * 96;        // 0..95

    const float4* p;
    if (g < 2) p = (const float4*)(zl + (size_t)b * 15360) + ((g & 1) * 96 + c);
    else       p = (const float4*)(zv + (size_t)b * 27648) + ((g & 1) * 96 + c);

    float acc[4] = {0.f, 0.f, 0.f, 0.f};
    if (g < 2) {
        #pragma unroll
        for (int t0 = 0; t0 < 20; t0 += 10) {
            float4 vb[10];
            #pragma unroll
            for (int u = 0; u < 10; ++u) vb[u] = p[(t0 + u) * 192];
            #pragma unroll
            for (int u = 0; u < 10; ++u) {
                float w = wl[t0 + u];
                acc[0] = fmaf(vb[u].x, w, acc[0]);
                acc[1] = fmaf(vb[u].y, w, acc[1]);
                acc[2] = fmaf(vb[u].z, w, acc[2]);
                acc[3] = fmaf(vb[u].w, w, acc[3]);
            }
        }
    } else {
        #pragma unroll
        for (int t0 = 0; t0 < 36; t0 += 9) {
            float4 vb[9];
            #pragma unroll
            for (int u = 0; u < 9; ++u) vb[u] = p[(t0 + u) * 192];
            #pragma unroll
            for (int u = 0; u < 9; ++u) {
                float w = wv[t0 + u];
                acc[0] = fmaf(vb[u].x, w, acc[0]);
                acc[1] = fmaf(vb[u].y, w, acc[1]);
                acc[2] = fmaf(vb[u].z, w, acc[2]);
                acc[3] = fmaf(vb[u].w, w, acc[3]);
            }
        }
    }

    float bl = blp[0], bv = bvp[0];

    if (g == 1) {                 // sig1
        float4 o;
        o.x = softplusf(acc[0] + bl) + 1e-7f;
        o.y = softplusf(acc[1] + bl) + 1e-7f;
        o.z = softplusf(acc[2] + bl) + 1e-7f;
        o.w = softplusf(acc[3] + bl) + 1e-7f;
        *(float4*)(SG + c * 4) = o;
    } else if (g == 2) {          // mu2
        *(float4*)(MU2 + c * 4) =
            make_float4(acc[0] + bv, acc[1] + bv, acc[2] + bv, acc[3] + bv);
    } else if (g == 3) {          // sig2
        float4 o;
        o.x = softplusf(acc[0] + bv) + 1e-7f;
        o.y = softplusf(acc[1] + bv) + 1e-7f;
        o.z = softplusf(acc[2] + bv) + 1e-7f;
        o.w = softplusf(acc[3] + bv) + 1e-7f;
        *(float4*)(SG + 384 + c * 4) = o;
    }
    __syncthreads();

    float con = 0.f;
    if (g == 0) {
        float4 e1v = ((const float4*)eps1)[b * 96 + c];
        float4 e2v = ((const float4*)eps2)[b * 96 + c];
        float4 g1 = *(const float4*)(SG + c * 4);
        float4 m2 = *(const float4*)(MU2 + c * 4);
        float4 g2 = *(const float4*)(SG + 384 + c * 4);
        float e1a[4] = {e1v.x, e1v.y, e1v.z, e1v.w};
        float e2a[4] = {e2v.x, e2v.y, e2v.z, e2v.w};
        float g1a[4] = {g1.x, g1.y, g1.z, g1.w};
        float g2a[4] = {g2.x, g2.y, g2.z, g2.w};
        float m2a[4] = {m2.x, m2.y, m2.z, m2.w};
        float s1o[4], s2o[4];
        #pragma unroll
        for (int j = 0; j < 4; ++j) {
            float mu1 = acc[j] + bl;
            float mu2 = m2a[j];
            float sg1 = g1a[j], sg2 = g2a[j];
            float e1 = e1a[j], e2 = e2a[j];
            float sv1 = fmaf(sg1, e1, mu1);
            float sv2 = fmaf(sg2, e2, mu2);
            s1o[j] = sv1; s2o[j] = sv2;
            float z12 = (sv1 - mu2) / sg2;
            float z21 = (sv2 - mu1) / sg1;
            con += -0.5f * (e1 * e1 + e2 * e2) + 0.5f * z12 * z12 + 0.5f * z21 * z21;
        }
        ((float4*)s1)[b * 96 + c] = make_float4(s1o[0], s1o[1], s1o[2], s1o[3]);
        ((float4*)s2)[b * 96 + c] = make_float4(s2o[0], s2o[1], s2o[2], s2o[3]);
    }

    #pragma unroll
    for (int m = 1; m < 64; m <<= 1) con += __shfl_xor(con, m);
    if ((tid & 63) == 0) pr[tid >> 6] = con;
    __syncthreads();
    if (tid == 0)
        atomicAdd(&accum[0], pr[0] + pr[1] + pr[2] + pr[3] + pr[4] + pr[5]);
}

// ---------------- B: Axb = s1 @ W1x^T + b1, By = s2 @ W1y^T ----------------
// 32b x 64k tile (round-1 traffic) but 512 threads (8 waves/block, ~2-4
// waves/SIMD) so LDS latency in the h-loop is hidden. 4 outputs/thread.
__global__ __launch_bounds__(512) void k_gemm(
    const float* __restrict__ s1, const float* __restrict__ s2,
    const float* __restrict__ W1, const float* __restrict__ b1,
    float* __restrict__ Axb, float* __restrict__ By)
{
    __shared__ float Ss[32][36];   // [h][b]
    __shared__ float Ws[32][68];   // [h][k]
    int z = blockIdx.z;
    const float* S = z ? s2 : s1;
    float* Out = z ? By : Axb;
    int wofs = z ? HIDV : 0;
    int b0 = blockIdx.x * 32;
    int k0 = blockIdx.y * 64;
    int tid = threadIdx.x;
    int srow = tid >> 3, sc = tid & 7;   // tid<256: S loader (32b x 8 quads)
    int wrow = tid >> 3, wc = tid & 7;   // all: W loader (64k x 8 quads)
    int krow = k0 + wrow;
    int tx = tid & 15, ty = tid >> 4;    // tx: k-quad (64k), ty: b (32)

    float4 ps, pw;
    auto ld = [&](int hc) {
        if (tid < 256) ps = *(const float4*)&S[(b0 + srow) * HIDV + hc + sc * 4];
        pw = (krow < MLPH) ? *(const float4*)&W1[krow * DD + wofs + hc + wc * 4]
                           : make_float4(0.f, 0.f, 0.f, 0.f);
    };
    ld(0);
    v2f acc[2];
    acc[0] = (v2f){0.f, 0.f}; acc[1] = (v2f){0.f, 0.f};

    for (int ch = 0; ch < 12; ++ch) {
        __syncthreads();
        if (tid < 256) {
            Ss[sc * 4 + 0][srow] = ps.x; Ss[sc * 4 + 1][srow] = ps.y;
            Ss[sc * 4 + 2][srow] = ps.z; Ss[sc * 4 + 3][srow] = ps.w;
        }
        Ws[wc * 4 + 0][wrow] = pw.x; Ws[wc * 4 + 1][wrow] = pw.y;
        Ws[wc * 4 + 2][wrow] = pw.z; Ws[wc * 4 + 3][wrow] = pw.w;
        __syncthreads();
        if (ch < 11) ld((ch + 1) * 32);
        #pragma unroll
        for (int h = 0; h < 32; ++h) {
            float sv = Ss[h][ty];                       // broadcast, conflict-free
            float4 wq = *(const float4*)&Ws[h][tx * 4]; // 16B-aligned, 2-way
            acc[0] = __builtin_elementwise_fma((v2f){sv, sv}, (v2f){wq.x, wq.y}, acc[0]);
            acc[1] = __builtin_elementwise_fma((v2f){sv, sv}, (v2f){wq.z, wq.w}, acc[1]);
        }
    }
    int bb = b0 + ty;
    int k = k0 + tx * 4;
    float vraw[4] = {acc[0].x, acc[0].y, acc[1].x, acc[1].y};
    float o[4];
    #pragma unroll
    for (int j = 0; j < 4; ++j) {
        int kj = k + j;
        float v = vraw[j];
        if (!z) v += b1[kj < MLPH ? kj : 0];
        o[j] = (kj < MLPH) ? v : 0.f;
    }
    *(float4*)&Out[bb * MLPP + k] = make_float4(o[0], o[1], o[2], o[3]);
}

// ---------------- C: T0 sum — one wave per row, float4 loads ----------------
__global__ __launch_bounds__(256) void k_t0(
    const float* __restrict__ Axb, const float* __restrict__ By,
    const float* __restrict__ W2, const float* __restrict__ b2,
    float* __restrict__ accum)
{
    int tid = threadIdx.x;
    int w = tid >> 6, l = tid & 63;
    int b = blockIdx.x * 4 + w;
    const float4* A4 = (const float4*)(Axb + b * MLPP);
    const float4* B4 = (const float4*)(By + b * MLPP);
    const float4* W4 = (const float4*)W2;
    float t = 0.f;
    {
        float4 a = A4[l], bb = B4[l], ww = W4[l];   // k = 4l, 0..255 < 300
        t = fmaf(fmaxf(a.x + bb.x, 0.f), ww.x, t);
        t = fmaf(fmaxf(a.y + bb.y, 0.f), ww.y, t);
        t = fmaf(fmaxf(a.z + bb.z, 0.f), ww.z, t);
        t = fmaf(fmaxf(a.w + bb.w, 0.f), ww.w, t);
    }
    if (l < 11) {                                   // k = 256+4l, 296..299 max
        float4 a = A4[64 + l], bb = B4[64 + l], ww = W4[64 + l];
        t = fmaf(fmaxf(a.x + bb.x, 0.f), ww.x, t);
        t = fmaf(fmaxf(a.y + bb.y, 0.f), ww.y, t);
        t = fmaf(fmaxf(a.z + bb.z, 0.f), ww.z, t);
        t = fmaf(fmaxf(a.w + bb.w, 0.f), ww.w, t);
    }
    #pragma unroll
    for (int m = 1; m < 64; m <<= 1) t += __shfl_xor(t, m);
    if (l == 0) atomicAdd(&accum[1], softplusf(t + b2[0]));
}

// ---------------- D: pair kernel, 64x64 tile, 1024 threads ----------------
// Same 256-block / 64x64 tiling as the 310us baseline (lowest global traffic;
// k-split is INVALID: exp() needs the full k-sum). Occupancy fix is inside the
// block: 1024 thr = 16 waves = 4 waves/SIMD (vs 1 before) hides the ~120cy
// LDS latency of the k-loop. 4 outputs/thread (2j x 2i). Pad 66: v2f reads
// 8B-aligned + 2-way banks; scalar stores 4-way (1.58x, minor).
__global__ __launch_bounds__(1024) void k_pairs(
    const float* __restrict__ Axb, const float* __restrict__ By,
    const int* __restrict__ perm, const float* __restrict__ W2,
    const float* __restrict__ b2, float* __restrict__ sumexp)
{
    __shared__ float As[64][66];   // [k][j]
    __shared__ float Bs[64][66];   // [k][i]
    __shared__ float w2s[MLPP];
    int tid = threadIdx.x;
    int j0 = blockIdx.x * 64;
    int i0 = blockIdx.y * 64;
    if (tid < MLPP) w2s[tid] = (tid < MLPH) ? W2[tid] : 0.f;
    int jj = tid >> 4;         // 0..63 (row: j for As, i for Bs)
    int kk = tid & 15;         // 0..15 (k-float4 within 64-chunk)
    int tx = tid & 31;         // j-pair (32 pairs = 64 j)
    int ty2 = tid >> 5;        // 0..31: i-pair (x2 = 64 i)
    int prow = perm[i0 + jj];

    float4 pa, pb;
    auto ld = [&](int kc) {
        pa = *(const float4*)&Axb[(j0 + jj) * MLPP + kc + kk * 4];
        pb = *(const float4*)&By[prow * MLPP + kc + kk * 4];
    };
    ld(0);
    v2f acc2[2];               // [i2], j-pair packed
    acc2[0] = (v2f){0.f, 0.f};
    acc2[1] = (v2f){0.f, 0.f};

    for (int ch = 0; ch < 5; ++ch) {
        __syncthreads();
        int kq = kk * 4;
        As[kq + 0][jj] = pa.x; As[kq + 1][jj] = pa.y;
        As[kq + 2][jj] = pa.z; As[kq + 3][jj] = pa.w;
        Bs[kq + 0][jj] = pb.x; Bs[kq + 1][jj] = pb.y;
        Bs[kq + 2][jj] = pb.z; Bs[kq + 3][jj] = pb.w;
        __syncthreads();
        if (ch < 4) ld((ch + 1) * 64);
        int kc = ch * 64;
        #pragma unroll
        for (int k = 0; k < 64; ++k) {
            float w = w2s[kc + k];
            v2f wv2 = (v2f){w, w};
            v2f av = *(const v2f*)&As[k][tx * 2];   // 8B-aligned, 2-way banks
            float b0v = Bs[k][ty2 * 2];             // 2 distinct/wave: broadcast
            float b1v = Bs[k][ty2 * 2 + 1];
            v2f t0v = av + (v2f){b0v, b0v};
            t0v = __builtin_elementwise_max(t0v, (v2f){0.f, 0.f});
            acc2[0] = __builtin_elementwise_fma(t0v, wv2, acc2[0]);
            v2f t1v = av + (v2f){b1v, b1v};
            t1v = __builtin_elementwise_max(t1v, (v2f){0.f, 0.f});
            acc2[1] = __builtin_elementwise_fma(t1v, wv2, acc2[1]);
        }
    }
    float b2v = b2[0];
    #pragma unroll
    for (int i2 = 0; i2 < 2; ++i2) {
        float ssum = (1.f + expf(acc2[i2].x + b2v)) + (1.f + expf(acc2[i2].y + b2v));
        ssum += __shfl_xor(ssum, 1);   // reduce over tx within 32-lane half
        ssum += __shfl_xor(ssum, 2);
        ssum += __shfl_xor(ssum, 4);
        ssum += __shfl_xor(ssum, 8);
        ssum += __shfl_xor(ssum, 16);
        if (tx == 0) atomicAdd(&sumexp[i0 + ty2 * 2 + i2], ssum);
    }
}

// ---------------- E: final scalar ----------------
__global__ __launch_bounds__(256) void k_final(
    const float* __restrict__ accum, const float* __restrict__ sumexp,
    float* __restrict__ out)
{
    int tid = threadIdx.x;
    float s = 0.f;
    for (int i = tid; i < BB; i += 256) s += logf(sumexp[i]);
    #pragma unroll
    for (int m = 1; m < 64; m <<= 1) s += __shfl_xor(s, m);
    __shared__ float red[4];
    if ((tid & 63) == 0) red[tid >> 6] = s;
    __syncthreads();
    if (tid == 0) {
        float lse_mean = (red[0] + red[1] + red[2] + red[3]) / (float)BB;
        float d_skl = accum[0] / (2.f * (float)BB);
        float t0_mean = accum[1] / (float)BB;
        float lower = t0_mean - (lse_mean - logf((float)BB));
        out[0] = d_skl - lower;
    }
}

extern "C" void kernel_launch(void* const* d_in, const int* in_sizes, int n_in,
                              void* d_out, int out_size, void* d_ws, size_t ws_size,
                              hipStream_t stream)
{
    const float* zl     = (const float*)d_in[0];
    const float* zv     = (const float*)d_in[1];
    const float* fc_l_w = (const float*)d_in[2];
    const float* fc_l_b = (const float*)d_in[3];
    const float* fc_v_w = (const float*)d_in[4];
    const float* fc_v_b = (const float*)d_in[5];
    const float* W1     = (const float*)d_in[6];
    const float* b1     = (const float*)d_in[7];
    const float* W2     = (const float*)d_in[8];
    const float* b2     = (const float*)d_in[9];
    const float* eps1   = (const float*)d_in[10];
    const float* eps2   = (const float*)d_in[11];
    const int*   perm   = (const int*)d_in[12];
    float* out = (float*)d_out;

    float* ws     = (float*)d_ws;
    float* accum  = ws;                    // 16
    float* sumexp = ws + 16;               // 1024
    float* s1     = ws + 16 + BB;          // B*384
    float* s2     = s1 + BB * HIDV;        // B*384
    float* Axb    = s2 + BB * HIDV;        // B*320
    float* By     = Axb + BB * MLPP;       // B*320

    k_init<<<5, 256, 0, stream>>>(ws);
    k_rs<<<BB, 384, 0, stream>>>(zl, zv, fc_l_w, fc_l_b, fc_v_w, fc_v_b,
                                 eps1, eps2, s1, s2, accum);
    k_gemm<<<dim3(32, 5, 2), 512, 0, stream>>>(s1, s2, W1, b1, Axb, By);
    k_t0<<<256, 256, 0, stream>>>(Axb, By, W2, b2, accum);
    k_pairs<<<dim3(16, 16), 1024, 0, stream>>>(Axb, By, perm, W2, b2, sumexp);
    k_final<<<1, 256, 0, stream>>>(accum, sumexp, out);
}